// Round 1
// baseline (1086.278 us; speedup 1.0000x reference)
//
#include <hip/hip_runtime.h>
#include <math.h>

#define IN_D 128
#define HID 64

// ---------------- utility kernels ----------------

__global__ void zero_ints(int* a, int n) {
    int i = blockIdx.x * blockDim.x + threadIdx.x;
    if (i < n) a[i] = 0;
}

__global__ void hist_kernel(const int* __restrict__ dst, int E, int* __restrict__ cnt) {
    int e = blockIdx.x * blockDim.x + threadIdx.x;
    if (e < E) atomicAdd(&cnt[dst[e]], 1);
}

// inclusive scan within 1024-blocks; writes row_ptr[i+1], block totals to blocksum
__global__ void scan1_kernel(const int* __restrict__ cnt, int N,
                             int* __restrict__ row_ptr, int* __restrict__ blocksum) {
    __shared__ int sm[1024];
    int i = blockIdx.x * 1024 + threadIdx.x;
    int v = (i < N) ? cnt[i] : 0;
    sm[threadIdx.x] = v;
    __syncthreads();
    for (int off = 1; off < 1024; off <<= 1) {
        int t = (threadIdx.x >= off) ? sm[threadIdx.x - off] : 0;
        __syncthreads();
        sm[threadIdx.x] += t;
        __syncthreads();
    }
    if (i < N) row_ptr[i + 1] = sm[threadIdx.x];
    if (threadIdx.x == 1023) blocksum[blockIdx.x] = sm[1023];
}

// single block: exclusive scan of blocksum (nb <= 1024)
__global__ void scan2_kernel(int* __restrict__ blocksum, int nb) {
    __shared__ int sm[1024];
    int v = (threadIdx.x < nb) ? blocksum[threadIdx.x] : 0;
    sm[threadIdx.x] = v;
    __syncthreads();
    for (int off = 1; off < 1024; off <<= 1) {
        int t = (threadIdx.x >= off) ? sm[threadIdx.x - off] : 0;
        __syncthreads();
        sm[threadIdx.x] += t;
        __syncthreads();
    }
    if (threadIdx.x < nb) blocksum[threadIdx.x] = sm[threadIdx.x] - v;  // exclusive
}

__global__ void scan3_kernel(int* __restrict__ row_ptr, int N, const int* __restrict__ blocksum) {
    int i = blockIdx.x * 1024 + threadIdx.x;
    if (i < N) row_ptr[i + 1] += blocksum[blockIdx.x];
    if (i == 0) row_ptr[0] = 0;
}

__global__ void scatter_kernel(const int* __restrict__ src, const int* __restrict__ dst, int E,
                               const int* __restrict__ row_ptr, int* __restrict__ cursor,
                               int* __restrict__ src_perm) {
    int e = blockIdx.x * blockDim.x + threadIdx.x;
    if (e < E) {
        int d = dst[e];
        int pos = row_ptr[d] + atomicAdd(&cursor[d], 1);
        src_perm[pos] = src[e];
    }
}

// deg (float) from int counts; nrm = dt^-1/2, invdt = dt^-1 with dt = lam*deg + (1-lam) = deg (lam=1)
__global__ void degnrm_from_cnt(const int* __restrict__ cnt, int N,
                                float* __restrict__ deg, float* __restrict__ nrm,
                                float* __restrict__ invdt) {
    int i = blockIdx.x * blockDim.x + threadIdx.x;
    if (i < N) {
        float d = (float)cnt[i];
        deg[i] = d;
        nrm[i] = 1.0f / sqrtf(d);
        invdt[i] = 1.0f / d;
    }
}

__global__ void nrm_from_deg(const float* __restrict__ deg, int N,
                             float* __restrict__ nrm, float* __restrict__ invdt) {
    int i = blockIdx.x * blockDim.x + threadIdx.x;
    if (i < N) {
        float dt = deg[i];
        nrm[i] = 1.0f / sqrtf(dt);
        invdt[i] = 1.0f / dt;
    }
}

// coef[e] = w[e] * nrm[src_perm[e]]   (w == nullptr -> w=1)
__global__ void coef_kernel(const int* __restrict__ src_perm, const float* __restrict__ w_perm,
                            const float* __restrict__ nrm, int E, float* __restrict__ coef) {
    int e = blockIdx.x * blockDim.x + threadIdx.x;
    if (e < E) {
        float c = nrm[src_perm[e]];
        if (w_perm) c *= w_perm[e];
        coef[e] = c;
    }
}

// ---------------- main compute kernels ----------------

// one wave per node, lane = feature dim
__global__ __launch_bounds__(256) void prop_kernel(
    const float* __restrict__ Yin, const float* __restrict__ X,
    const int* __restrict__ row_ptr, const int* __restrict__ src_perm,
    const float* __restrict__ coef, const float* __restrict__ nrm,
    const float* __restrict__ invdt, int N, float* __restrict__ Yout) {
    int wave = (blockIdx.x * blockDim.x + threadIdx.x) >> 6;
    int lane = threadIdx.x & 63;
    if (wave >= N) return;
    int r0 = row_ptr[wave], r1 = row_ptr[wave + 1];
    float acc = 0.0f;
    for (int jb = r0; jb < r1; jb += 64) {
        int m = r1 - jb;
        if (m > 64) m = 64;
        int sv = 0;
        float cv = 0.0f;
        if (lane < m) { sv = src_perm[jb + lane]; cv = coef[jb + lane]; }
        for (int t = 0; t < m; ++t) {
            int s = __shfl(sv, t, 64);
            float c = __shfl(cv, t, 64);
            acc += c * Yin[(size_t)s * HID + lane];
        }
    }
    size_t base = (size_t)wave * HID + lane;
    Yout[base] = 0.5f * Yin[base] + (0.5f * nrm[wave]) * acc + (0.5f * invdt[wave]) * X[base];
}

// attention: w_e = 1/max(sqrt(relu(||h_s-h_d||^2)+1e-7), tau) + 1e-9 ; deg = sum_e w_e per dst
__global__ __launch_bounds__(256) void attn_kernel(
    const float* __restrict__ Y, const int* __restrict__ row_ptr,
    const int* __restrict__ src_perm, int N,
    float* __restrict__ w_perm, float* __restrict__ deg) {
    int wv = (blockIdx.x * blockDim.x + threadIdx.x) >> 6;
    int lane = threadIdx.x & 63;
    if (wv >= N) return;
    int r0 = row_ptr[wv], r1 = row_ptr[wv + 1];
    float hd = Y[(size_t)wv * HID + lane];
    float dacc = 0.0f;
    for (int jb = r0; jb < r1; jb += 64) {
        int m = r1 - jb;
        if (m > 64) m = 64;
        int sv = (lane < m) ? src_perm[jb + lane] : 0;
        float wreg = 0.0f;
        for (int t = 0; t < m; ++t) {
            int s = __shfl(sv, t, 64);
            float d = Y[(size_t)s * HID + lane] - hd;
            float ss = d * d;
            #pragma unroll
            for (int o = 32; o >= 1; o >>= 1) ss += __shfl_xor(ss, o, 64);
            float w = fmaxf(ss, 0.0f) + 1e-7f;   // relu + eps
            w = sqrtf(w);                         // pow(w, 1 - 0.5*p_rho), p_rho=1
            w = fmaxf(w, 0.2f);                   // tau clamp
            w = 1.0f / w + 1e-9f;
            dacc += w;
            if (lane == t) wreg = w;
        }
        if (lane < m) w_perm[jb + lane] = wreg;
    }
    if (lane == 0) deg[wv] = dacc;
}

// X = feat @ W_bef + b_bef   (128 -> 64), wave per row, W in LDS
__global__ __launch_bounds__(256) void gemm1_kernel(
    const float* __restrict__ feat, const float* __restrict__ W,
    const float* __restrict__ b, int N, float* __restrict__ X) {
    __shared__ float Wl[IN_D * HID];
    for (int i = threadIdx.x; i < IN_D * HID; i += 256) Wl[i] = W[i];
    __syncthreads();
    int gw = (blockIdx.x * 256 + threadIdx.x) >> 6;
    int lane = threadIdx.x & 63;
    int nw = (gridDim.x * 256) >> 6;
    float bias = b[lane];
    for (int v = gw; v < N; v += nw) {
        float f0 = feat[(size_t)v * IN_D + lane];
        float f1 = feat[(size_t)v * IN_D + 64 + lane];
        float acc = bias;
        #pragma unroll
        for (int k = 0; k < 64; ++k) acc += __shfl(f0, k, 64) * Wl[k * HID + lane];
        #pragma unroll
        for (int k = 0; k < 64; ++k) acc += __shfl(f1, k, 64) * Wl[(64 + k) * HID + lane];
        X[(size_t)v * HID + lane] = acc;
    }
}

// out = relu(Y) @ W_aft + b_aft   (64 -> 64)
__global__ __launch_bounds__(256) void gemm2_kernel(
    const float* __restrict__ Y, const float* __restrict__ W,
    const float* __restrict__ b, int N, float* __restrict__ out) {
    __shared__ float Wl[HID * HID];
    for (int i = threadIdx.x; i < HID * HID; i += 256) Wl[i] = W[i];
    __syncthreads();
    int gw = (blockIdx.x * 256 + threadIdx.x) >> 6;
    int lane = threadIdx.x & 63;
    int nw = (gridDim.x * 256) >> 6;
    float bias = b[lane];
    for (int v = gw; v < N; v += nw) {
        float y = Y[(size_t)v * HID + lane];
        y = fmaxf(y, 0.0f);
        float acc = bias;
        #pragma unroll
        for (int k = 0; k < 64; ++k) acc += __shfl(y, k, 64) * Wl[k * HID + lane];
        out[(size_t)v * HID + lane] = acc;
    }
}

// ---------------- launch ----------------

extern "C" void kernel_launch(void* const* d_in, const int* in_sizes, int n_in,
                              void* d_out, int out_size, void* d_ws, size_t ws_size,
                              hipStream_t stream) {
    const float* feat  = (const float*)d_in[0];
    const float* W_bef = (const float*)d_in[1];
    const float* b_bef = (const float*)d_in[2];
    const float* W_aft = (const float*)d_in[3];
    const float* b_aft = (const float*)d_in[4];
    const int*   src   = (const int*)d_in[5];
    const int*   dst   = (const int*)d_in[6];

    const int N = in_sizes[0] / IN_D;
    const int E = in_sizes[5];

    // workspace carve-up (256B-aligned)
    char* p = (char*)d_ws;
    auto alloc = [&](size_t bytes) -> void* {
        void* r = (void*)p;
        p += (bytes + 255) & ~(size_t)255;
        return r;
    };
    float* X       = (float*)alloc((size_t)N * HID * 4);
    float* Ya      = (float*)alloc((size_t)N * HID * 4);
    float* Yb      = (float*)alloc((size_t)N * HID * 4);
    int*   cnt     = (int*)alloc((size_t)N * 4);
    int*   cursor  = (int*)alloc((size_t)N * 4);
    int*   row_ptr = (int*)alloc((size_t)(N + 1) * 4);
    int*   blocksum= (int*)alloc(4096);
    int*   src_perm= (int*)alloc((size_t)E * 4);
    float* w_perm  = (float*)alloc((size_t)E * 4);
    float* coef    = (float*)alloc((size_t)E * 4);
    float* deg     = (float*)alloc((size_t)N * 4);
    float* nrm     = (float*)alloc((size_t)N * 4);
    float* invdt   = (float*)alloc((size_t)N * 4);

    const int TB = 256;
    dim3 blk(TB);
    int gN   = (N + TB - 1) / TB;
    int gE   = (E + TB - 1) / TB;
    int gNW  = (N * 64 + TB - 1) / TB;     // wave-per-node kernels
    int nb   = (N + 1023) / 1024;          // scan blocks

    // --- CSR build ---
    zero_ints<<<gN, blk, 0, stream>>>(cnt, N);
    zero_ints<<<gN, blk, 0, stream>>>(cursor, N);
    hist_kernel<<<gE, blk, 0, stream>>>(dst, E, cnt);
    scan1_kernel<<<nb, 1024, 0, stream>>>(cnt, N, row_ptr, blocksum);
    scan2_kernel<<<1, 1024, 0, stream>>>(blocksum, nb);
    scan3_kernel<<<nb, 1024, 0, stream>>>(row_ptr, N, blocksum);
    degnrm_from_cnt<<<gN, blk, 0, stream>>>(cnt, N, deg, nrm, invdt);
    scatter_kernel<<<gE, blk, 0, stream>>>(src, dst, E, row_ptr, cursor, src_perm);

    // --- MLP before ---
    gemm1_kernel<<<512, blk, 0, stream>>>(feat, W_bef, b_bef, N, X);

    // --- phase 1: w = 1 ---
    coef_kernel<<<gE, blk, 0, stream>>>(src_perm, nullptr, nrm, E, coef);
    prop_kernel<<<gNW, blk, 0, stream>>>(X,  X, row_ptr, src_perm, coef, nrm, invdt, N, Ya);
    prop_kernel<<<gNW, blk, 0, stream>>>(Ya, X, row_ptr, src_perm, coef, nrm, invdt, N, Yb);
    prop_kernel<<<gNW, blk, 0, stream>>>(Yb, X, row_ptr, src_perm, coef, nrm, invdt, N, Ya);
    prop_kernel<<<gNW, blk, 0, stream>>>(Ya, X, row_ptr, src_perm, coef, nrm, invdt, N, Yb);

    // --- attention on Yb ---
    attn_kernel<<<gNW, blk, 0, stream>>>(Yb, row_ptr, src_perm, N, w_perm, deg);
    nrm_from_deg<<<gN, blk, 0, stream>>>(deg, N, nrm, invdt);
    coef_kernel<<<gE, blk, 0, stream>>>(src_perm, w_perm, nrm, E, coef);

    // --- phase 2: attention weights ---
    prop_kernel<<<gNW, blk, 0, stream>>>(Yb, X, row_ptr, src_perm, coef, nrm, invdt, N, Ya);
    prop_kernel<<<gNW, blk, 0, stream>>>(Ya, X, row_ptr, src_perm, coef, nrm, invdt, N, Yb);
    prop_kernel<<<gNW, blk, 0, stream>>>(Yb, X, row_ptr, src_perm, coef, nrm, invdt, N, Ya);
    prop_kernel<<<gNW, blk, 0, stream>>>(Ya, X, row_ptr, src_perm, coef, nrm, invdt, N, Yb);

    // --- MLP after ---
    gemm2_kernel<<<512, blk, 0, stream>>>(Yb, W_aft, b_aft, N, (float*)d_out);
}

// Round 2
// 714.548 us; speedup vs baseline: 1.5202x; 1.5202x over previous
//
#include <hip/hip_runtime.h>
#include <math.h>

#define IN_D 128
#define HID 64

// ---------------- utility kernels ----------------

__global__ void zero_ints(int* a, int n) {
    int i = blockIdx.x * blockDim.x + threadIdx.x;
    if (i < n) a[i] = 0;
}

__global__ void hist_kernel(const int* __restrict__ dst, int E, int* __restrict__ cnt) {
    int e = blockIdx.x * blockDim.x + threadIdx.x;
    if (e < E) atomicAdd(&cnt[dst[e]], 1);
}

// inclusive scan within 1024-blocks; writes row_ptr[i+1], block totals to blocksum
__global__ void scan1_kernel(const int* __restrict__ cnt, int N,
                             int* __restrict__ row_ptr, int* __restrict__ blocksum) {
    __shared__ int sm[1024];
    int i = blockIdx.x * 1024 + threadIdx.x;
    int v = (i < N) ? cnt[i] : 0;
    sm[threadIdx.x] = v;
    __syncthreads();
    for (int off = 1; off < 1024; off <<= 1) {
        int t = (threadIdx.x >= off) ? sm[threadIdx.x - off] : 0;
        __syncthreads();
        sm[threadIdx.x] += t;
        __syncthreads();
    }
    if (i < N) row_ptr[i + 1] = sm[threadIdx.x];
    if (threadIdx.x == 1023) blocksum[blockIdx.x] = sm[1023];
}

// single block: exclusive scan of blocksum (nb <= 1024)
__global__ void scan2_kernel(int* __restrict__ blocksum, int nb) {
    __shared__ int sm[1024];
    int v = (threadIdx.x < nb) ? blocksum[threadIdx.x] : 0;
    sm[threadIdx.x] = v;
    __syncthreads();
    for (int off = 1; off < 1024; off <<= 1) {
        int t = (threadIdx.x >= off) ? sm[threadIdx.x - off] : 0;
        __syncthreads();
        sm[threadIdx.x] += t;
        __syncthreads();
    }
    if (threadIdx.x < nb) blocksum[threadIdx.x] = sm[threadIdx.x] - v;  // exclusive
}

__global__ void scan3_kernel(int* __restrict__ row_ptr, int N, const int* __restrict__ blocksum) {
    int i = blockIdx.x * 1024 + threadIdx.x;
    if (i < N) row_ptr[i + 1] += blocksum[blockIdx.x];
    if (i == 0) row_ptr[0] = 0;
}

__global__ void scatter_kernel(const int* __restrict__ src, const int* __restrict__ dst, int E,
                               const int* __restrict__ row_ptr, int* __restrict__ cursor,
                               int* __restrict__ src_perm) {
    int e = blockIdx.x * blockDim.x + threadIdx.x;
    if (e < E) {
        int d = dst[e];
        int pos = row_ptr[d] + atomicAdd(&cursor[d], 1);
        src_perm[pos] = src[e];
    }
}

__global__ void degnrm_from_cnt(const int* __restrict__ cnt, int N,
                                float* __restrict__ nrm, float* __restrict__ invdt) {
    int i = blockIdx.x * blockDim.x + threadIdx.x;
    if (i < N) {
        float d = (float)cnt[i];
        nrm[i] = 1.0f / sqrtf(d);
        invdt[i] = 1.0f / d;
    }
}

__global__ void nrm_from_deg(const float* __restrict__ deg, int N,
                             float* __restrict__ nrm, float* __restrict__ invdt) {
    int i = blockIdx.x * blockDim.x + threadIdx.x;
    if (i < N) {
        float dt = deg[i];
        nrm[i] = 1.0f / sqrtf(dt);
        invdt[i] = 1.0f / dt;
    }
}

// coef[e] = w[e] * nrm[src_perm[e]]   (w == nullptr -> w=1)
__global__ void coef_kernel(const int* __restrict__ src_perm, const float* __restrict__ w_perm,
                            const float* __restrict__ nrm, int E, float* __restrict__ coef) {
    int e = blockIdx.x * blockDim.x + threadIdx.x;
    if (e < E) {
        float c = nrm[src_perm[e]];
        if (w_perm) c *= w_perm[e];
        coef[e] = c;
    }
}

// ---------------- main compute kernels ----------------

// one wave per node, lane = feature dim; 8 gathers in flight
__global__ __launch_bounds__(256) void prop_kernel(
    const float* __restrict__ Yin, const float* __restrict__ X,
    const int* __restrict__ row_ptr, const int* __restrict__ src_perm,
    const float* __restrict__ coef, const float* __restrict__ nrm,
    const float* __restrict__ invdt, int N, float* __restrict__ Yout) {
    int wave = (blockIdx.x * blockDim.x + threadIdx.x) >> 6;
    int lane = threadIdx.x & 63;
    if (wave >= N) return;
    int r0 = row_ptr[wave], r1 = row_ptr[wave + 1];
    float acc = 0.0f;
    for (int jb = r0; jb < r1; jb += 64) {
        int m = r1 - jb;
        if (m > 64) m = 64;
        int sv = 0;
        float cv = 0.0f;
        if (lane < m) { sv = src_perm[jb + lane]; cv = coef[jb + lane]; }
        for (int t = 0; t < m; t += 8) {
            float v[8], c[8];
            #pragma unroll
            for (int u = 0; u < 8; ++u) {
                int idx = t + u;
                int active = idx < m;
                if (!active) idx = 0;                       // clamp: safe lane
                int s = __shfl(sv, idx, 64);
                float cc = __shfl(cv, idx, 64);
                c[u] = active ? cc : 0.0f;
                v[u] = Yin[(size_t)s * HID + lane];          // 8 loads in flight
            }
            #pragma unroll
            for (int u = 0; u < 8; ++u) acc += c[u] * v[u];
        }
    }
    size_t base = (size_t)wave * HID + lane;
    Yout[base] = 0.5f * Yin[base] + (0.5f * nrm[wave]) * acc + (0.5f * invdt[wave]) * X[base];
}

// attention: w_e = 1/max(sqrt(relu(||h_s-h_d||^2)+1e-7), tau) + 1e-9 ; deg = sum_e w_e per dst
// 4 edges per batch, interleaved butterflies
__global__ __launch_bounds__(256) void attn_kernel(
    const float* __restrict__ Y, const int* __restrict__ row_ptr,
    const int* __restrict__ src_perm, int N,
    float* __restrict__ w_perm, float* __restrict__ deg) {
    int wv = (blockIdx.x * blockDim.x + threadIdx.x) >> 6;
    int lane = threadIdx.x & 63;
    if (wv >= N) return;
    int r0 = row_ptr[wv], r1 = row_ptr[wv + 1];
    float hd = Y[(size_t)wv * HID + lane];
    float dacc = 0.0f;
    for (int jb = r0; jb < r1; jb += 64) {
        int m = r1 - jb;
        if (m > 64) m = 64;
        int sv = (lane < m) ? src_perm[jb + lane] : 0;
        float wreg = 0.0f;
        for (int t = 0; t < m; t += 4) {
            float ss[4];
            int act[4];
            #pragma unroll
            for (int u = 0; u < 4; ++u) {
                int idx = t + u;
                act[u] = idx < m;
                if (!act[u]) idx = 0;
                int s = __shfl(sv, idx, 64);
                float d = Y[(size_t)s * HID + lane] - hd;    // 4 gathers in flight
                ss[u] = d * d;
            }
            #pragma unroll
            for (int o = 32; o >= 1; o >>= 1) {
                #pragma unroll
                for (int u = 0; u < 4; ++u) ss[u] += __shfl_xor(ss[u], o, 64);
            }
            #pragma unroll
            for (int u = 0; u < 4; ++u) {
                float w = fmaxf(ss[u], 0.0f) + 1e-7f;  // relu + eps
                w = sqrtf(w);                           // pow(w, 1 - 0.5*p_rho), p_rho=1
                w = fmaxf(w, 0.2f);                     // tau clamp
                w = 1.0f / w + 1e-9f;
                if (act[u]) {
                    dacc += w;
                    if (lane == t + u) wreg = w;
                }
            }
        }
        if (lane < m) w_perm[jb + lane] = wreg;
    }
    if (lane == 0) deg[wv] = dacc;
}

// X = feat @ W_bef + b_bef  (128 -> 64). Block: 8 rows/iter, thread = (rowpair, col).
__global__ __launch_bounds__(256) void gemm1_kernel(
    const float* __restrict__ feat, const float* __restrict__ W,
    const float* __restrict__ b, int N, float* __restrict__ X) {
    __shared__ float Wl[IN_D * HID];     // 32 KB
    __shared__ float featL[8 * IN_D];    // 4 KB
    for (int i = threadIdx.x; i < IN_D * HID; i += 256) Wl[i] = W[i];
    int c = threadIdx.x & 63;
    int rsub = threadIdx.x >> 6;         // 0..3, uniform per wave
    float bias = b[c];
    int ngroups = N / 8;                 // N = 100000 -> 12500 exactly
    const float4* feat4 = (const float4*)feat;
    for (int g = blockIdx.x; g < ngroups; g += gridDim.x) {
        __syncthreads();
        ((float4*)featL)[threadIdx.x] = feat4[(size_t)g * 256 + threadIdx.x];
        __syncthreads();
        const float4* f0 = (const float4*)&featL[rsub * IN_D];
        const float4* f1 = (const float4*)&featL[(rsub + 4) * IN_D];
        float acc0 = bias, acc1 = bias;
        #pragma unroll
        for (int k4 = 0; k4 < IN_D / 4; ++k4) {
            float4 a = f0[k4];
            float4 e = f1[k4];
            float w0 = Wl[(4 * k4 + 0) * HID + c];
            float w1 = Wl[(4 * k4 + 1) * HID + c];
            float w2 = Wl[(4 * k4 + 2) * HID + c];
            float w3 = Wl[(4 * k4 + 3) * HID + c];
            acc0 += a.x * w0 + a.y * w1 + a.z * w2 + a.w * w3;
            acc1 += e.x * w0 + e.y * w1 + e.z * w2 + e.w * w3;
        }
        size_t row = (size_t)g * 8;
        X[(row + rsub) * HID + c] = acc0;
        X[(row + rsub + 4) * HID + c] = acc1;
    }
}

// out = relu(Y) @ W_aft + b_aft  (64 -> 64)
__global__ __launch_bounds__(256) void gemm2_kernel(
    const float* __restrict__ Y, const float* __restrict__ W,
    const float* __restrict__ b, int N, float* __restrict__ out) {
    __shared__ float Wl[HID * HID];      // 16 KB
    __shared__ float Yl[8 * HID];        // 2 KB
    for (int i = threadIdx.x; i < HID * HID; i += 256) Wl[i] = W[i];
    int c = threadIdx.x & 63;
    int rsub = threadIdx.x >> 6;
    float bias = b[c];
    int ngroups = N / 8;
    const float4* Y4 = (const float4*)Y;
    for (int g = blockIdx.x; g < ngroups; g += gridDim.x) {
        __syncthreads();
        if (threadIdx.x < 128) {
            float4 v = Y4[(size_t)g * 128 + threadIdx.x];
            v.x = fmaxf(v.x, 0.0f); v.y = fmaxf(v.y, 0.0f);
            v.z = fmaxf(v.z, 0.0f); v.w = fmaxf(v.w, 0.0f);
            ((float4*)Yl)[threadIdx.x] = v;
        }
        __syncthreads();
        const float4* f0 = (const float4*)&Yl[rsub * HID];
        const float4* f1 = (const float4*)&Yl[(rsub + 4) * HID];
        float acc0 = bias, acc1 = bias;
        #pragma unroll
        for (int k4 = 0; k4 < HID / 4; ++k4) {
            float4 a = f0[k4];
            float4 e = f1[k4];
            float w0 = Wl[(4 * k4 + 0) * HID + c];
            float w1 = Wl[(4 * k4 + 1) * HID + c];
            float w2 = Wl[(4 * k4 + 2) * HID + c];
            float w3 = Wl[(4 * k4 + 3) * HID + c];
            acc0 += a.x * w0 + a.y * w1 + a.z * w2 + a.w * w3;
            acc1 += e.x * w0 + e.y * w1 + e.z * w2 + e.w * w3;
        }
        size_t row = (size_t)g * 8;
        out[(row + rsub) * HID + c] = acc0;
        out[(row + rsub + 4) * HID + c] = acc1;
    }
}

// ---------------- launch ----------------

extern "C" void kernel_launch(void* const* d_in, const int* in_sizes, int n_in,
                              void* d_out, int out_size, void* d_ws, size_t ws_size,
                              hipStream_t stream) {
    const float* feat  = (const float*)d_in[0];
    const float* W_bef = (const float*)d_in[1];
    const float* b_bef = (const float*)d_in[2];
    const float* W_aft = (const float*)d_in[3];
    const float* b_aft = (const float*)d_in[4];
    const int*   src   = (const int*)d_in[5];
    const int*   dst   = (const int*)d_in[6];

    const int N = in_sizes[0] / IN_D;
    const int E = in_sizes[5];

    // workspace carve-up (256B-aligned)
    char* p = (char*)d_ws;
    auto alloc = [&](size_t bytes) -> void* {
        void* r = (void*)p;
        p += (bytes + 255) & ~(size_t)255;
        return r;
    };
    float* X       = (float*)alloc((size_t)N * HID * 4);
    float* Ya      = (float*)alloc((size_t)N * HID * 4);
    float* Yb      = (float*)alloc((size_t)N * HID * 4);
    int*   cnt     = (int*)alloc((size_t)N * 4);
    int*   cursor  = (int*)alloc((size_t)N * 4);
    int*   row_ptr = (int*)alloc((size_t)(N + 1) * 4);
    int*   blocksum= (int*)alloc(4096);
    int*   src_perm= (int*)alloc((size_t)E * 4);
    float* w_perm  = (float*)alloc((size_t)E * 4);
    float* coef    = (float*)alloc((size_t)E * 4);
    float* deg     = (float*)alloc((size_t)N * 4);
    float* nrm     = (float*)alloc((size_t)N * 4);
    float* invdt   = (float*)alloc((size_t)N * 4);

    const int TB = 256;
    dim3 blk(TB);
    int gN   = (N + TB - 1) / TB;
    int gE   = (E + TB - 1) / TB;
    int gNW  = (N * 64 + TB - 1) / TB;     // wave-per-node kernels
    int nb   = (N + 1023) / 1024;          // scan blocks

    // --- CSR build ---
    zero_ints<<<gN, blk, 0, stream>>>(cnt, N);
    zero_ints<<<gN, blk, 0, stream>>>(cursor, N);
    hist_kernel<<<gE, blk, 0, stream>>>(dst, E, cnt);
    scan1_kernel<<<nb, 1024, 0, stream>>>(cnt, N, row_ptr, blocksum);
    scan2_kernel<<<1, 1024, 0, stream>>>(blocksum, nb);
    scan3_kernel<<<nb, 1024, 0, stream>>>(row_ptr, N, blocksum);
    degnrm_from_cnt<<<gN, blk, 0, stream>>>(cnt, N, nrm, invdt);
    scatter_kernel<<<gE, blk, 0, stream>>>(src, dst, E, row_ptr, cursor, src_perm);

    // --- MLP before ---
    gemm1_kernel<<<2048, blk, 0, stream>>>(feat, W_bef, b_bef, N, X);

    // --- phase 1: w = 1 ---
    coef_kernel<<<gE, blk, 0, stream>>>(src_perm, nullptr, nrm, E, coef);
    prop_kernel<<<gNW, blk, 0, stream>>>(X,  X, row_ptr, src_perm, coef, nrm, invdt, N, Ya);
    prop_kernel<<<gNW, blk, 0, stream>>>(Ya, X, row_ptr, src_perm, coef, nrm, invdt, N, Yb);
    prop_kernel<<<gNW, blk, 0, stream>>>(Yb, X, row_ptr, src_perm, coef, nrm, invdt, N, Ya);
    prop_kernel<<<gNW, blk, 0, stream>>>(Ya, X, row_ptr, src_perm, coef, nrm, invdt, N, Yb);

    // --- attention on Yb ---
    attn_kernel<<<gNW, blk, 0, stream>>>(Yb, row_ptr, src_perm, N, w_perm, deg);
    nrm_from_deg<<<gN, blk, 0, stream>>>(deg, N, nrm, invdt);
    coef_kernel<<<gE, blk, 0, stream>>>(src_perm, w_perm, nrm, E, coef);

    // --- phase 2: attention weights ---
    prop_kernel<<<gNW, blk, 0, stream>>>(Yb, X, row_ptr, src_perm, coef, nrm, invdt, N, Ya);
    prop_kernel<<<gNW, blk, 0, stream>>>(Ya, X, row_ptr, src_perm, coef, nrm, invdt, N, Yb);
    prop_kernel<<<gNW, blk, 0, stream>>>(Yb, X, row_ptr, src_perm, coef, nrm, invdt, N, Ya);
    prop_kernel<<<gNW, blk, 0, stream>>>(Ya, X, row_ptr, src_perm, coef, nrm, invdt, N, Yb);

    // --- MLP after ---
    gemm2_kernel<<<512, blk, 0, stream>>>(Yb, W_aft, b_aft, N, (float*)d_out);
}